// Round 1
// baseline (597.092 us; speedup 1.0000x reference)
//
#include <hip/hip_runtime.h>
#include <cstdint>

#define EPS 1e-5f

typedef __attribute__((ext_vector_type(8))) short bf16x8;   // 8 bf16 in 4 VGPRs
typedef __attribute__((ext_vector_type(4))) float f32x4;

// ---------- bf16 helpers (RNE) ----------
__device__ __forceinline__ unsigned short f2bf(float x) {
    uint32_t u = __float_as_uint(x);
    u += 0x7fffu + ((u >> 16) & 1u);
    return (unsigned short)(u >> 16);
}
__device__ __forceinline__ uint32_t pack2(float lo, float hi) {
    return (uint32_t)f2bf(lo) | ((uint32_t)f2bf(hi) << 16);
}
__device__ __forceinline__ float bflo(uint32_t p) { return __uint_as_float(p << 16); }
__device__ __forceinline__ float bfhi(uint32_t p) { return __uint_as_float(p & 0xffff0000u); }

// ---------- async global->LDS, 16B per lane ----------
__device__ __forceinline__ void async_ld16(const void* g, const void* l) {
    __builtin_amdgcn_global_load_lds(
        (const __attribute__((address_space(1))) uint32_t*)(uintptr_t)g,
        (__attribute__((address_space(3))) uint32_t*)(uint32_t)(uintptr_t)l,
        16, 0, 0);
}

// ---------- CSR build ----------
__global__ __launch_bounds__(256) void zero_kernel(int* __restrict__ p, int n) {
    int i = blockIdx.x * 256 + threadIdx.x;
    if (i < n) p[i] = 0;
}

__global__ __launch_bounds__(256) void count_kernel(const int* __restrict__ ei,
                                                    int* __restrict__ deg, int E) {
    int e = blockIdx.x * 256 + threadIdx.x;
    if (e < E) atomicAdd(&deg[ei[E + e]], 1);
}

__global__ __launch_bounds__(1024) void scan_kernel(const int* __restrict__ deg,
                                                    int* __restrict__ offsets,
                                                    int* __restrict__ cursor,
                                                    float* __restrict__ deginv, int N) {
    __shared__ int part[1024];
    const int t = threadIdx.x;
    const int CH = (N + 1023) >> 10;
    const int base = t * CH;
    int s = 0;
    for (int j = 0; j < CH; ++j) {
        int idx = base + j;
        if (idx < N) s += deg[idx];
    }
    part[t] = s;
    __syncthreads();
    for (int off = 1; off < 1024; off <<= 1) {
        int add = (t >= off) ? part[t - off] : 0;
        __syncthreads();
        part[t] += add;
        __syncthreads();
    }
    int run = (t == 0) ? 0 : part[t - 1];
    for (int j = 0; j < CH; ++j) {
        int idx = base + j;
        if (idx < N) {
            offsets[idx] = run;
            cursor[idx]  = run;
            int dgi = deg[idx];
            deginv[idx] = 1.0f / (float)(dgi > 0 ? dgi : 1);
            run += dgi;
        }
    }
    if (t == 1023) offsets[N] = run;
}

__global__ __launch_bounds__(256) void fill_kernel(const int* __restrict__ ei,
                                                   int* __restrict__ cursor,
                                                   int* __restrict__ csr, int E) {
    int e = blockIdx.x * 256 + threadIdx.x;
    if (e < E) {
        int dd = ei[E + e];
        int slot = atomicAdd(&cursor[dd], 1);
        csr[slot] = ei[e];
    }
}

// ---------- embedding + BN(layer 0), bf16 into A_cat[:, 0:512] ----------
__global__ __launch_bounds__(256) void embed_bn_kernel(const int* __restrict__ tok,
                                                       const int* __restrict__ pos,
                                                       const float* __restrict__ vemb,
                                                       const float* __restrict__ pemb,
                                                       const float* __restrict__ gamma,
                                                       const float* __restrict__ beta,
                                                       const float* __restrict__ mean,
                                                       const float* __restrict__ var,
                                                       uint32_t* __restrict__ Acat, int N) {
    const int idx = blockIdx.x * 256 + threadIdx.x;   // one per 4 columns
    if (idx >= N * 128) return;
    const int row = idx >> 7;
    const int c = (idx & 127) * 4;
    const int tk = tok[row];
    const int ps = pos[row];
    const float4 a = *(const float4*)&vemb[(size_t)tk * 512 + c];
    const float4 b = *(const float4*)&pemb[(size_t)ps * 512 + c];
    const float4 g = *(const float4*)&gamma[c];
    const float4 be = *(const float4*)&beta[c];
    const float4 mn = *(const float4*)&mean[c];
    const float4 vr = *(const float4*)&var[c];
    const float y0 = (a.x + b.x - mn.x) * (g.x * rsqrtf(vr.x + EPS)) + be.x;
    const float y1 = (a.y + b.y - mn.y) * (g.y * rsqrtf(vr.y + EPS)) + be.y;
    const float y2 = (a.z + b.z - mn.z) * (g.z * rsqrtf(vr.z + EPS)) + be.z;
    const float y3 = (a.w + b.w - mn.w) * (g.w * rsqrtf(vr.w + EPS)) + be.w;
    uint2 o;
    o.x = pack2(y0, y1);
    o.y = pack2(y2, y3);
    *(uint2*)&Acat[(size_t)row * 512 + (c >> 1)] = o;
}

// ---------- per-layer: W_cat bf16 [512 rows][1024 k] = [W_root | W_rel] (B^T layout) ----------
__global__ __launch_bounds__(256) void castW_kernel(const float* __restrict__ Wroot,
                                                    const float* __restrict__ Wrel,
                                                    uint32_t* __restrict__ Wcat) {
    const int p = blockIdx.x * 256 + threadIdx.x;   // 262144 pairs total
    const int o  = p >> 9;
    const int dp = p & 511;
    float2 v;
    if (dp < 256) v = *(const float2*)&Wroot[(size_t)o * 512 + dp * 2];
    else          v = *(const float2*)&Wrel[(size_t)o * 512 + (dp - 256) * 2];
    Wcat[(size_t)o * 512 + dp] = pack2(v.x, v.y);
}

// ---------- mean aggregation (CSR gather, wave-per-node, 16B loads, x4 pipeline) ----------
__global__ __launch_bounds__(256) void aggregate_kernel(uint32_t* __restrict__ Acat,
                                                        const int* __restrict__ offsets,
                                                        const int* __restrict__ csr,
                                                        const float* __restrict__ deginv,
                                                        int N) {
    const int node = blockIdx.x * 4 + (threadIdx.x >> 6);
    if (node >= N) return;
    const int lane = threadIdx.x & 63;
    const int col = lane * 4;                 // uint index within 256-uint bn half
    const int beg = offsets[node];
    const int end = offsets[node + 1];
    float s[8] = {0.f, 0.f, 0.f, 0.f, 0.f, 0.f, 0.f, 0.f};
    int e = beg;
    for (; e + 4 <= end; e += 4) {
        const int i0 = csr[e];
        const int i1 = csr[e + 1];
        const int i2 = csr[e + 2];
        const int i3 = csr[e + 3];
        const uint4 p0 = *(const uint4*)&Acat[(size_t)i0 * 512 + col];
        const uint4 p1 = *(const uint4*)&Acat[(size_t)i1 * 512 + col];
        const uint4 p2 = *(const uint4*)&Acat[(size_t)i2 * 512 + col];
        const uint4 p3 = *(const uint4*)&Acat[(size_t)i3 * 512 + col];
        s[0] += bflo(p0.x) + bflo(p1.x) + bflo(p2.x) + bflo(p3.x);
        s[1] += bfhi(p0.x) + bfhi(p1.x) + bfhi(p2.x) + bfhi(p3.x);
        s[2] += bflo(p0.y) + bflo(p1.y) + bflo(p2.y) + bflo(p3.y);
        s[3] += bfhi(p0.y) + bfhi(p1.y) + bfhi(p2.y) + bfhi(p3.y);
        s[4] += bflo(p0.z) + bflo(p1.z) + bflo(p2.z) + bflo(p3.z);
        s[5] += bfhi(p0.z) + bfhi(p1.z) + bfhi(p2.z) + bfhi(p3.z);
        s[6] += bflo(p0.w) + bflo(p1.w) + bflo(p2.w) + bflo(p3.w);
        s[7] += bfhi(p0.w) + bfhi(p1.w) + bfhi(p2.w) + bfhi(p3.w);
    }
    for (; e < end; ++e) {
        const int i0 = csr[e];
        const uint4 p0 = *(const uint4*)&Acat[(size_t)i0 * 512 + col];
        s[0] += bflo(p0.x); s[1] += bfhi(p0.x);
        s[2] += bflo(p0.y); s[3] += bfhi(p0.y);
        s[4] += bflo(p0.z); s[5] += bfhi(p0.z);
        s[6] += bflo(p0.w); s[7] += bfhi(p0.w);
    }
    const float inv = deginv[node];
    uint4 o;
    o.x = pack2(s[0] * inv, s[1] * inv);
    o.y = pack2(s[2] * inv, s[3] * inv);
    o.z = pack2(s[4] * inv, s[5] * inv);
    o.w = pack2(s[6] * inv, s[7] * inv);
    *(uint4*)&Acat[(size_t)node * 512 + 256 + col] = o;
}

// ---------- pipelined GEMM: out = relu(A_cat[M,1024] @ W_cat[512,1024]^T + bias) ----------
// BM=256, BN=128, BK=64, 512 threads (8 waves, 4Mx2N), 3-stage LDS pipeline with
// counted vmcnt(6) at tile boundaries (loads stay in flight across barriers),
// XOR-swizzled LDS (pre-swizzled global source, linear global_load_lds dest),
// s_setprio around MFMA clusters, XCD-grouped block decode for A-panel L2 reuse.
// last layer: writes f32 to C. otherwise: applies NEXT layer's BN, bf16 to Abn.
__global__ __launch_bounds__(512, 2)
void gemm_pipe(const unsigned short* __restrict__ A,
               const unsigned short* __restrict__ B,
               const float* __restrict__ bias,
               const float* __restrict__ gamma,
               const float* __restrict__ beta,
               const float* __restrict__ mean,
               const float* __restrict__ var,
               int last,
               float* __restrict__ C,
               unsigned short* __restrict__ Abn,
               int M, int mt, int rpx) {
    extern __shared__ unsigned short lds[];   // 3 bufs * 24576 shorts = 144 KiB
    // per buffer: A tile [256][64] at shorts [0,16384), B tile [128][64] at [16384,24576)

    // XCD-grouped decode: hardware round-robins bid%8 across XCDs; give each XCD
    // rpx consecutive row-tiles, with the 4 column-siblings of a row-tile at
    // consecutive slots so they co-reside on one XCD L2 (A panel fetched once).
    const int bid = blockIdx.x;
    const int xcd = bid & 7;
    const int slt = bid >> 3;
    const int bm  = xcd * rpx + (slt >> 2);
    const int bn  = slt & 3;
    if (bm >= mt) return;

    const int t    = threadIdx.x;
    const int lane = t & 63;
    const int wid  = t >> 6;
    const int wr   = wid >> 1;    // 0..3: wave row (64 rows each)
    const int wc   = wid & 1;     // 0..1: wave col (64 cols each)
    const int lm   = lane & 15;
    const int q    = lane >> 4;

    // ---- staging source pointers (pre-swizzled column slot: rule #21) ----
    const int tr = t >> 3;                       // row within 64-row chunk
    const int sg = (t & 7) ^ (tr & 7);           // swizzled 16B slot in global
    int r0 = bm * 256 + tr;        if (r0 >= M) r0 = M - 1;
    int r1 = bm * 256 + 64  + tr;  if (r1 >= M) r1 = M - 1;
    int r2 = bm * 256 + 128 + tr;  if (r2 >= M) r2 = M - 1;
    int r3 = bm * 256 + 192 + tr;  if (r3 >= M) r3 = M - 1;
    const unsigned short* gA0 = A + (size_t)r0 * 1024 + sg * 8;
    const unsigned short* gA1 = A + (size_t)r1 * 1024 + sg * 8;
    const unsigned short* gA2 = A + (size_t)r2 * 1024 + sg * 8;
    const unsigned short* gA3 = A + (size_t)r3 * 1024 + sg * 8;
    const unsigned short* gB0 = B + (size_t)(bn * 128 + tr)      * 1024 + sg * 8;
    const unsigned short* gB1 = B + (size_t)(bn * 128 + 64 + tr) * 1024 + sg * 8;
    const int ldst = t * 8;                      // linear LDS dest (shorts), 16B/lane

#define STAGE_H0(KT, LP) do {                                          \
        async_ld16(gA0 + (KT) * 64, (LP) + 0 * 4096 + ldst);           \
        async_ld16(gA1 + (KT) * 64, (LP) + 1 * 4096 + ldst);           \
        async_ld16(gA2 + (KT) * 64, (LP) + 2 * 4096 + ldst);           \
    } while (0)
#define STAGE_H1(KT, LP) do {                                          \
        async_ld16(gA3 + (KT) * 64, (LP) + 3 * 4096 + ldst);           \
        async_ld16(gB0 + (KT) * 64, (LP) + 16384 + 0 * 4096 + ldst);   \
        async_ld16(gB1 + (KT) * 64, (LP) + 16384 + 1 * 4096 + ldst);   \
    } while (0)

    // ---- fragment read bases (shorts); row&7 == lm&7 so swizzle is per-lane const
    const int aB = (wr * 64 + lm) * 64;          // + mf*1024 + slot*8
    const int bB = 16384 + (wc * 64 + lm) * 64;  // + nf*1024 + slot*8
    const int sw = lm & 7;
    const int k0 = ((0 + q) ^ sw) * 8;           // kk=0 swizzled slot offset
    const int k1 = ((4 + q) ^ sw) * 8;           // kk=1

    const f32x4 zero = {0.f, 0.f, 0.f, 0.f};
    f32x4 acc[4][4];
#pragma unroll
    for (int i = 0; i < 4; ++i)
#pragma unroll
        for (int j = 0; j < 4; ++j) acc[i][j] = zero;

#define MFMA_PHASE(KOFF) do {                                                   \
        bf16x8 afr[4], bfr[4];                                                  \
        _Pragma("unroll") for (int mf = 0; mf < 4; ++mf)                        \
            afr[mf] = *(const bf16x8*)&Lb[aB + mf * 1024 + (KOFF)];             \
        _Pragma("unroll") for (int nf = 0; nf < 4; ++nf)                        \
            bfr[nf] = *(const bf16x8*)&Lb[bB + nf * 1024 + (KOFF)];             \
        __builtin_amdgcn_s_setprio(1);                                          \
        _Pragma("unroll") for (int mf = 0; mf < 4; ++mf)                        \
            _Pragma("unroll") for (int nf = 0; nf < 4; ++nf)                    \
                acc[mf][nf] = __builtin_amdgcn_mfma_f32_16x16x32_bf16(          \
                    afr[mf], bfr[nf], acc[mf][nf], 0, 0, 0);                    \
        __builtin_amdgcn_s_setprio(0);                                          \
    } while (0)

    // prologue: stage tiles 0 and 1 (12 loads in flight)
    {
        unsigned short* L0 = lds;
        STAGE_H0(0, L0); STAGE_H1(0, L0);
        unsigned short* L1 = lds + 24576;
        STAGE_H0(1, L1); STAGE_H1(1, L1);
    }

    // main loop: 16 K-tiles of 64. Boundary: wait own oldest 6 loads (tile kt),
    // then barrier -> all waves' tile-kt data landed. Next-next tile staged
    // during compute; its buffer's prior readers finished (barrier proves it).
#pragma unroll
    for (int kt = 0; kt < 16; ++kt) {
        unsigned short* Lb = lds + (kt % 3) * 24576;
        unsigned short* Ln = lds + ((kt + 2) % 3) * 24576;
        if (kt < 15) asm volatile("s_waitcnt vmcnt(6)" ::: "memory");
        else         asm volatile("s_waitcnt vmcnt(0)" ::: "memory");
        __builtin_amdgcn_s_barrier();
        __builtin_amdgcn_sched_barrier(0);

        if (kt + 2 < 16) STAGE_H0(kt + 2, Ln);
        MFMA_PHASE(k0);
        if (kt + 2 < 16) STAGE_H1(kt + 2, Ln);
        MFMA_PHASE(k1);
    }

    // epilogue: C/D layout col=lane&15, row=(lane>>4)*4+reg (m89-verified)
#pragma unroll
    for (int nf = 0; nf < 4; ++nf) {
        const int col = bn * 128 + wc * 64 + nf * 16 + lm;
        const float bsv = bias[col];
        float bn_inv = 0.f, bn_mb = 0.f, bn_bt = 0.f;
        if (!last) {
            bn_inv = gamma[col] * rsqrtf(var[col] + EPS);
            bn_mb  = mean[col];
            bn_bt  = beta[col];
        }
#pragma unroll
        for (int mf = 0; mf < 4; ++mf) {
            const int row0 = bm * 256 + wr * 64 + mf * 16 + q * 4;
#pragma unroll
            for (int i = 0; i < 4; ++i) {
                const int row = row0 + i;
                if (row < M) {
                    float v = acc[mf][nf][i] + bsv;
                    v = v > 0.f ? v : 0.f;
                    if (last) {
                        C[(size_t)row * 512 + col] = v;
                    } else {
                        const float y = (v - bn_mb) * bn_inv + bn_bt;
                        Abn[(size_t)row * 1024 + col] = f2bf(y);
                    }
                }
            }
        }
    }
#undef STAGE_H0
#undef STAGE_H1
#undef MFMA_PHASE
}

extern "C" void kernel_launch(void* const* d_in, const int* in_sizes, int n_in,
                              void* d_out, int out_size, void* d_ws, size_t ws_size,
                              hipStream_t stream) {
    const int*   tokens = (const int*)d_in[0];
    const int*   posi   = (const int*)d_in[1];
    const int*   ei     = (const int*)d_in[2];
    const float* vemb   = (const float*)d_in[3];
    const float* pemb   = (const float*)d_in[4];
    const float* gamma  = (const float*)d_in[5];
    const float* beta   = (const float*)d_in[6];
    const float* mean   = (const float*)d_in[7];
    const float* var    = (const float*)d_in[8];
    const float* Wrel   = (const float*)d_in[9];
    const float* brel   = (const float*)d_in[10];
    const float* Wroot  = (const float*)d_in[11];

    const int N = in_sizes[0];
    const int E = in_sizes[2] / 2;
    float* out = (float*)d_out;

    char* w = (char*)d_ws;
    int*      deg     = (int*)(w);                  // N ints
    int*      offsets = (int*)(w + 80000);          // N+1 ints
    int*      cursor  = (int*)(w + 160016);         // N ints
    float*    deginv  = (float*)(w + 240032);       // N floats
    int*      csr     = (int*)(w + 320048);         // E ints
    uint32_t* Acat    = (uint32_t*)(w + 1600064);   // [N][512] uints = [N][1024] bf16
    uint32_t* Wcat    = (uint32_t*)(w + 42560064);  // [512][512] uints = [512][1024] bf16

    // allow 144 KiB dynamic LDS for the pipelined GEMM (once; harmless if no-op)
    static bool s_attr = false;
    if (!s_attr) {
        (void)hipFuncSetAttribute(reinterpret_cast<const void*>(gemm_pipe),
                                  hipFuncAttributeMaxDynamicSharedMemorySize, 147456);
        s_attr = true;
    }

    // CSR build (ws re-poisoned each call -> deg must be zeroed here)
    zero_kernel<<<(N + 255) / 256, 256, 0, stream>>>(deg, N);
    count_kernel<<<(E + 255) / 256, 256, 0, stream>>>(ei, deg, E);
    scan_kernel<<<1, 1024, 0, stream>>>(deg, offsets, cursor, deginv, N);
    fill_kernel<<<(E + 255) / 256, 256, 0, stream>>>(ei, cursor, csr, E);

    // embed + layer-0 BN directly into Acat (no f32 x round-trip)
    embed_bn_kernel<<<(N * 128 + 255) / 256, 256, 0, stream>>>(
        tokens, posi, vemb, pemb, gamma, beta, mean, var, Acat, N);

    const int mt  = (N + 255) >> 8;    // 256-row tiles (79)
    const int rpx = (mt + 7) >> 3;     // row-tiles per XCD (10)
    const int gb  = 8 * rpx * 4;       // grid (320; tail blocks exit early)

    for (int l = 0; l < 4; ++l) {
        const int last = (l == 3);
        castW_kernel<<<1024, 256, 0, stream>>>(Wroot + (size_t)l * 262144,
                                               Wrel + (size_t)l * 262144, Wcat);
        aggregate_kernel<<<(N + 3) / 4, 256, 0, stream>>>(Acat, offsets, csr, deginv, N);
        gemm_pipe<<<gb, 512, 147456, stream>>>(
            (const unsigned short*)Acat, (const unsigned short*)Wcat, brel + l * 512,
            gamma + (l + 1) * 512, beta + (l + 1) * 512,
            mean + (l + 1) * 512, var + (l + 1) * 512,
            last, out, (unsigned short*)Acat, N, mt, rpx);
    }
}

// Round 5
// 575.082 us; speedup vs baseline: 1.0383x; 1.0383x over previous
//
#include <hip/hip_runtime.h>
#include <cstdint>

#define EPS 1e-5f

typedef __attribute__((ext_vector_type(8))) short bf16x8;   // 8 bf16 in 4 VGPRs
typedef __attribute__((ext_vector_type(4))) float f32x4;

// ---------- bf16 helpers (RNE) ----------
__device__ __forceinline__ unsigned short f2bf(float x) {
    uint32_t u = __float_as_uint(x);
    u += 0x7fffu + ((u >> 16) & 1u);
    return (unsigned short)(u >> 16);
}
__device__ __forceinline__ uint32_t pack2(float lo, float hi) {
    return (uint32_t)f2bf(lo) | ((uint32_t)f2bf(hi) << 16);
}
__device__ __forceinline__ float bflo(uint32_t p) { return __uint_as_float(p << 16); }
__device__ __forceinline__ float bfhi(uint32_t p) { return __uint_as_float(p & 0xffff0000u); }

// ---------- async global->LDS, 16B per lane ----------
__device__ __forceinline__ void async_ld16(const void* g, const void* l) {
    __builtin_amdgcn_global_load_lds(
        (const __attribute__((address_space(1))) uint32_t*)(uintptr_t)g,
        (__attribute__((address_space(3))) uint32_t*)(uint32_t)(uintptr_t)l,
        16, 0, 0);
}

// ---------- CSR build ----------
__global__ __launch_bounds__(256) void zero_kernel(int* __restrict__ p, int n) {
    int i = blockIdx.x * 256 + threadIdx.x;
    if (i < n) p[i] = 0;
}

__global__ __launch_bounds__(256) void count_kernel(const int* __restrict__ ei,
                                                    int* __restrict__ deg, int E) {
    int e = blockIdx.x * 256 + threadIdx.x;
    if (e < E) atomicAdd(&deg[ei[E + e]], 1);
}

__global__ __launch_bounds__(1024) void scan_kernel(const int* __restrict__ deg,
                                                    int* __restrict__ offsets,
                                                    int* __restrict__ cursor,
                                                    float* __restrict__ deginv, int N) {
    __shared__ int part[1024];
    const int t = threadIdx.x;
    const int CH = (N + 1023) >> 10;
    const int base = t * CH;
    int s = 0;
    for (int j = 0; j < CH; ++j) {
        int idx = base + j;
        if (idx < N) s += deg[idx];
    }
    part[t] = s;
    __syncthreads();
    for (int off = 1; off < 1024; off <<= 1) {
        int add = (t >= off) ? part[t - off] : 0;
        __syncthreads();
        part[t] += add;
        __syncthreads();
    }
    int run = (t == 0) ? 0 : part[t - 1];
    for (int j = 0; j < CH; ++j) {
        int idx = base + j;
        if (idx < N) {
            offsets[idx] = run;
            cursor[idx]  = run;
            int dgi = deg[idx];
            deginv[idx] = 1.0f / (float)(dgi > 0 ? dgi : 1);
            run += dgi;
        }
    }
    if (t == 1023) offsets[N] = run;
}

__global__ __launch_bounds__(256) void fill_kernel(const int* __restrict__ ei,
                                                   int* __restrict__ cursor,
                                                   int* __restrict__ csr, int E) {
    int e = blockIdx.x * 256 + threadIdx.x;
    if (e < E) {
        int dd = ei[E + e];
        int slot = atomicAdd(&cursor[dd], 1);
        csr[slot] = ei[e];
    }
}

// ---------- embedding + BN(layer 0), bf16 into A_cat[:, 0:512] ----------
__global__ __launch_bounds__(256) void embed_bn_kernel(const int* __restrict__ tok,
                                                       const int* __restrict__ pos,
                                                       const float* __restrict__ vemb,
                                                       const float* __restrict__ pemb,
                                                       const float* __restrict__ gamma,
                                                       const float* __restrict__ beta,
                                                       const float* __restrict__ mean,
                                                       const float* __restrict__ var,
                                                       uint32_t* __restrict__ Acat, int N) {
    const int idx = blockIdx.x * 256 + threadIdx.x;   // one per 4 columns
    if (idx >= N * 128) return;
    const int row = idx >> 7;
    const int c = (idx & 127) * 4;
    const int tk = tok[row];
    const int ps = pos[row];
    const float4 a = *(const float4*)&vemb[(size_t)tk * 512 + c];
    const float4 b = *(const float4*)&pemb[(size_t)ps * 512 + c];
    const float4 g = *(const float4*)&gamma[c];
    const float4 be = *(const float4*)&beta[c];
    const float4 mn = *(const float4*)&mean[c];
    const float4 vr = *(const float4*)&var[c];
    const float y0 = (a.x + b.x - mn.x) * (g.x * rsqrtf(vr.x + EPS)) + be.x;
    const float y1 = (a.y + b.y - mn.y) * (g.y * rsqrtf(vr.y + EPS)) + be.y;
    const float y2 = (a.z + b.z - mn.z) * (g.z * rsqrtf(vr.z + EPS)) + be.z;
    const float y3 = (a.w + b.w - mn.w) * (g.w * rsqrtf(vr.w + EPS)) + be.w;
    uint2 o;
    o.x = pack2(y0, y1);
    o.y = pack2(y2, y3);
    *(uint2*)&Acat[(size_t)row * 512 + (c >> 1)] = o;
}

// ---------- per-layer: W_cat bf16 [512 rows][1024 k] = [W_root | W_rel] (B^T layout) ----------
__global__ __launch_bounds__(256) void castW_kernel(const float* __restrict__ Wroot,
                                                    const float* __restrict__ Wrel,
                                                    uint32_t* __restrict__ Wcat) {
    const int p = blockIdx.x * 256 + threadIdx.x;   // 262144 pairs total
    const int o  = p >> 9;
    const int dp = p & 511;
    float2 v;
    if (dp < 256) v = *(const float2*)&Wroot[(size_t)o * 512 + dp * 2];
    else          v = *(const float2*)&Wrel[(size_t)o * 512 + (dp - 256) * 2];
    Wcat[(size_t)o * 512 + dp] = pack2(v.x, v.y);
}

// ---------- mean aggregation (CSR gather, wave-per-node, 16B loads, x4 pipeline) ----------
__global__ __launch_bounds__(256) void aggregate_kernel(uint32_t* __restrict__ Acat,
                                                        const int* __restrict__ offsets,
                                                        const int* __restrict__ csr,
                                                        const float* __restrict__ deginv,
                                                        int N) {
    const int node = blockIdx.x * 4 + (threadIdx.x >> 6);
    if (node >= N) return;
    const int lane = threadIdx.x & 63;
    const int col = lane * 4;                 // uint index within 256-uint bn half
    const int beg = offsets[node];
    const int end = offsets[node + 1];
    float s[8] = {0.f, 0.f, 0.f, 0.f, 0.f, 0.f, 0.f, 0.f};
    int e = beg;
    for (; e + 4 <= end; e += 4) {
        const int i0 = csr[e];
        const int i1 = csr[e + 1];
        const int i2 = csr[e + 2];
        const int i3 = csr[e + 3];
        const uint4 p0 = *(const uint4*)&Acat[(size_t)i0 * 512 + col];
        const uint4 p1 = *(const uint4*)&Acat[(size_t)i1 * 512 + col];
        const uint4 p2 = *(const uint4*)&Acat[(size_t)i2 * 512 + col];
        const uint4 p3 = *(const uint4*)&Acat[(size_t)i3 * 512 + col];
        s[0] += bflo(p0.x) + bflo(p1.x) + bflo(p2.x) + bflo(p3.x);
        s[1] += bfhi(p0.x) + bfhi(p1.x) + bfhi(p2.x) + bfhi(p3.x);
        s[2] += bflo(p0.y) + bflo(p1.y) + bflo(p2.y) + bflo(p3.y);
        s[3] += bfhi(p0.y) + bfhi(p1.y) + bfhi(p2.y) + bfhi(p3.y);
        s[4] += bflo(p0.z) + bflo(p1.z) + bflo(p2.z) + bflo(p3.z);
        s[5] += bfhi(p0.z) + bfhi(p1.z) + bfhi(p2.z) + bfhi(p3.z);
        s[6] += bflo(p0.w) + bflo(p1.w) + bflo(p2.w) + bflo(p3.w);
        s[7] += bfhi(p0.w) + bfhi(p1.w) + bfhi(p2.w) + bfhi(p3.w);
    }
    for (; e < end; ++e) {
        const int i0 = csr[e];
        const uint4 p0 = *(const uint4*)&Acat[(size_t)i0 * 512 + col];
        s[0] += bflo(p0.x); s[1] += bfhi(p0.x);
        s[2] += bflo(p0.y); s[3] += bfhi(p0.y);
        s[4] += bflo(p0.z); s[5] += bfhi(p0.z);
        s[6] += bflo(p0.w); s[7] += bfhi(p0.w);
    }
    const float inv = deginv[node];
    uint4 o;
    o.x = pack2(s[0] * inv, s[1] * inv);
    o.y = pack2(s[2] * inv, s[3] * inv);
    o.z = pack2(s[4] * inv, s[5] * inv);
    o.w = pack2(s[6] * inv, s[7] * inv);
    *(uint4*)&Acat[(size_t)node * 512 + 256 + col] = o;
}

// ---------- 8-phase GEMM (m201 template port): relu(A[M,1024] @ W[512,1024]^T + bias) ----------
// BM=256, BN=256, 512 thr (8 waves: 2M x 4N, 128x64 per wave). Pipeline unit = K-half of 32.
// 4 rotating half-buffers (32 KiB each = 128 KiB LDS). Per half (ONE barrier):
//   vmcnt(W) -> s_barrier   (publish: all waves' half-j loads landed; also proves all
//                            reads of buf (j-1) finished, so STAGE(j+3) below is WAR-safe)
//   phase0: 8x ds_read_b128 (afr mh0 + b0..b3), STAGE_A(j+3), lgkmcnt(0), 16 MFMA
//   phase1: 4x ds_read_b128 (afr mh1),          STAGE_B(j+3), lgkmcnt(0), 16 MFMA
// FIFO: 4 loads/half, 3-half lead -> vmcnt(8) guarantees half j landed (j+1,j+2 in flight).
__global__ __launch_bounds__(512, 2)
void gemm_8ph(const unsigned short* __restrict__ A,
              const unsigned short* __restrict__ B,
              const float* __restrict__ bias,
              const float* __restrict__ gamma,
              const float* __restrict__ beta,
              const float* __restrict__ mean,
              const float* __restrict__ var,
              int last,
              float* __restrict__ C,
              unsigned short* __restrict__ Abn,
              int M, int mt, int rpx) {
    extern __shared__ unsigned short lds[];   // 4 slots * 16384 shorts (A 8192 | B 8192)

    // XCD pairing: bid%8 round-robins XCDs; put both bn of a bm on one XCD.
    const int bid = blockIdx.x;
    const int bm  = (bid & 7) * rpx + (bid >> 4);
    const int bn  = (bid >> 3) & 1;
    if (bm >= mt) return;

    const int t    = threadIdx.x;
    const int lane = t & 63;
    const int wid  = t >> 6;
    const int wr   = wid >> 2;    // 0..1: 128 rows
    const int wc   = wid & 3;     // 0..3: 64 cols
    const int lm   = lane & 15;
    const int q    = lane >> 4;

    // ---- staging: 4 loads per K-half (2 A + 2 B); pre-swizzled global slot ----
    const int trow = t >> 2;                         // 0..127
    const int sg   = (t & 3) ^ ((t >> 3) & 3);       // swizzled 8-short slot
    int a0 = bm * 256 + trow;       if (a0 >= M) a0 = M - 1;
    int a1 = bm * 256 + 128 + trow; if (a1 >= M) a1 = M - 1;
    const unsigned short* gA0 = A + (size_t)a0 * 1024 + sg * 8;
    const unsigned short* gA1 = A + (size_t)a1 * 1024 + sg * 8;
    const unsigned short* gB0 = B + (size_t)(bn * 256 + trow) * 1024 + sg * 8;
    const unsigned short* gB1 = B + (size_t)(bn * 256 + 128 + trow) * 1024 + sg * 8;
    const int ldst = t * 8;                          // linear LDS dest (16B/lane)

#define STAGE_A(J, BUF) do {                                                   \
        async_ld16(gA0 + (J) * 32, lds + (BUF) * 16384 + ldst);                \
        async_ld16(gA1 + (J) * 32, lds + (BUF) * 16384 + 4096 + ldst);         \
    } while (0)
#define STAGE_B(J, BUF) do {                                                   \
        async_ld16(gB0 + (J) * 32, lds + (BUF) * 16384 + 8192 + ldst);         \
        async_ld16(gB1 + (J) * 32, lds + (BUF) * 16384 + 12288 + ldst);        \
    } while (0)

    // ---- fragment read bases (swizzled slot folds to per-lane const) ----
    const int asw  = (q ^ ((lm >> 1) & 3)) * 8;
    const int aoff = (wr * 128 + lm) * 32 + asw;          // + mf*512
    const int boff = 8192 + (wc * 64 + lm) * 32 + asw;    // + nf*512

    const f32x4 zero = {0.f, 0.f, 0.f, 0.f};
    f32x4 acc[8][4];
#pragma unroll
    for (int i = 0; i < 8; ++i)
#pragma unroll
        for (int j = 0; j < 4; ++j) acc[i][j] = zero;

#define MFMA16(MH, AF, B0, B1, B2, B3)                                          \
        __builtin_amdgcn_s_setprio(1);                                          \
        _Pragma("unroll") for (int mf = 0; mf < 4; ++mf) {                      \
            acc[(MH) * 4 + mf][0] = __builtin_amdgcn_mfma_f32_16x16x32_bf16(    \
                AF[mf], B0, acc[(MH) * 4 + mf][0], 0, 0, 0);                    \
            acc[(MH) * 4 + mf][1] = __builtin_amdgcn_mfma_f32_16x16x32_bf16(    \
                AF[mf], B1, acc[(MH) * 4 + mf][1], 0, 0, 0);                    \
            acc[(MH) * 4 + mf][2] = __builtin_amdgcn_mfma_f32_16x16x32_bf16(    \
                AF[mf], B2, acc[(MH) * 4 + mf][2], 0, 0, 0);                    \
            acc[(MH) * 4 + mf][3] = __builtin_amdgcn_mfma_f32_16x16x32_bf16(    \
                AF[mf], B3, acc[(MH) * 4 + mf][3], 0, 0, 0);                    \
        }                                                                       \
        __builtin_amdgcn_s_setprio(0);

#define HALF_BODY(JJ, JG, W0LIT, DOSTG) do {                                    \
        const unsigned short* Lp = lds + (JJ) * 16384;                          \
        /* publish half JG: own loads done -> rendezvous -> buffer valid */     \
        asm volatile("s_waitcnt vmcnt(" W0LIT ")" ::: "memory");                \
        __builtin_amdgcn_s_barrier();                                           \
        __builtin_amdgcn_sched_barrier(0);                                      \
        bf16x8 b0, b1, b2, b3;                                                  \
        { /* phase 0: m-half 0 */                                               \
            bf16x8 af[4];                                                       \
            _Pragma("unroll") for (int mf = 0; mf < 4; ++mf)                    \
                af[mf] = *(const bf16x8*)(Lp + aoff + mf * 512);                \
            b0 = *(const bf16x8*)(Lp + boff + 0 * 512);                         \
            b1 = *(const bf16x8*)(Lp + boff + 1 * 512);                         \
            b2 = *(const bf16x8*)(Lp + boff + 2 * 512);                         \
            b3 = *(const bf16x8*)(Lp + boff + 3 * 512);                         \
            if (DOSTG) { STAGE_A((JG) + 3, ((JJ) + 3) & 3); }                   \
            asm volatile("s_waitcnt lgkmcnt(0)" ::: "memory");                  \
            __builtin_amdgcn_sched_barrier(0);                                  \
            MFMA16(0, af, b0, b1, b2, b3)                                       \
        }                                                                       \
        { /* phase 1: m-half 1 */                                               \
            bf16x8 af[4];                                                       \
            _Pragma("unroll") for (int mf = 0; mf < 4; ++mf)                    \
                af[mf] = *(const bf16x8*)(Lp + aoff + (4 + mf) * 512);          \
            if (DOSTG) { STAGE_B((JG) + 3, ((JJ) + 3) & 3); }                   \
            asm volatile("s_waitcnt lgkmcnt(0)" ::: "memory");                  \
            __builtin_amdgcn_sched_barrier(0);                                  \
            MFMA16(1, af, b0, b1, b2, b3)                                       \
        }                                                                       \
    } while (0)

    // prologue: stage halves 0,1,2 (12 loads in flight)
    STAGE_A(0, 0); STAGE_B(0, 0);
    STAGE_A(1, 1); STAGE_B(1, 1);
    STAGE_A(2, 2); STAGE_B(2, 2);

    // main: K=1024 -> 32 halves. jt rolled, jj unrolled (static slots/immediates).
    for (int jt = 0; jt < 7; ++jt) {
        const int j0 = jt * 4;
        HALF_BODY(0, j0 + 0, "8", 1);
        HALF_BODY(1, j0 + 1, "8", 1);
        HALF_BODY(2, j0 + 2, "8", 1);
        HALF_BODY(3, j0 + 3, "8", 1);
    }
    // tail: j=28 stages 31; then drain 8 -> 8 -> 4 -> 0
    HALF_BODY(0, 28, "8", 1);
    HALF_BODY(1, 29, "8", 0);
    HALF_BODY(2, 30, "4", 0);
    HALF_BODY(3, 31, "0", 0);

    // epilogue: C/D layout col=lane&15, row=(lane>>4)*4+reg (m89-verified)
#pragma unroll
    for (int nf = 0; nf < 4; ++nf) {
        const int col = bn * 256 + wc * 64 + nf * 16 + lm;
        const float bsv = bias[col];
        float bn_inv = 0.f, bn_mb = 0.f, bn_bt = 0.f;
        if (!last) {
            bn_inv = gamma[col] * rsqrtf(var[col] + EPS);
            bn_mb  = mean[col];
            bn_bt  = beta[col];
        }
#pragma unroll
        for (int mf = 0; mf < 8; ++mf) {
            const int row0 = bm * 256 + wr * 128 + mf * 16 + q * 4;
#pragma unroll
            for (int i = 0; i < 4; ++i) {
                const int row = row0 + i;
                if (row < M) {
                    float v = acc[mf][nf][i] + bsv;
                    v = v > 0.f ? v : 0.f;
                    if (last) {
                        C[(size_t)row * 512 + col] = v;
                    } else {
                        const float y = (v - bn_mb) * bn_inv + bn_bt;
                        Abn[(size_t)row * 1024 + col] = f2bf(y);
                    }
                }
            }
        }
    }
#undef STAGE_A
#undef STAGE_B
#undef MFMA16
#undef HALF_BODY
}

extern "C" void kernel_launch(void* const* d_in, const int* in_sizes, int n_in,
                              void* d_out, int out_size, void* d_ws, size_t ws_size,
                              hipStream_t stream) {
    const int*   tokens = (const int*)d_in[0];
    const int*   posi   = (const int*)d_in[1];
    const int*   ei     = (const int*)d_in[2];
    const float* vemb   = (const float*)d_in[3];
    const float* pemb   = (const float*)d_in[4];
    const float* gamma  = (const float*)d_in[5];
    const float* beta   = (const float*)d_in[6];
    const float* mean   = (const float*)d_in[7];
    const float* var    = (const float*)d_in[8];
    const float* Wrel   = (const float*)d_in[9];
    const float* brel   = (const float*)d_in[10];
    const float* Wroot  = (const float*)d_in[11];

    const int N = in_sizes[0];
    const int E = in_sizes[2] / 2;
    float* out = (float*)d_out;

    char* w = (char*)d_ws;
    int*      deg     = (int*)(w);                  // N ints
    int*      offsets = (int*)(w + 80000);          // N+1 ints
    int*      cursor  = (int*)(w + 160016);         // N ints
    float*    deginv  = (float*)(w + 240032);       // N floats
    int*      csr     = (int*)(w + 320048);         // E ints
    uint32_t* Acat    = (uint32_t*)(w + 1600064);   // [N][512] uints = [N][1024] bf16
    uint32_t* Wcat    = (uint32_t*)(w + 42560064);  // [512][512] uints = [512][1024] bf16

    // allow 128 KiB dynamic LDS for the 8-phase GEMM (once; harmless if no-op)
    static bool s_attr = false;
    if (!s_attr) {
        (void)hipFuncSetAttribute(reinterpret_cast<const void*>(gemm_8ph),
                                  hipFuncAttributeMaxDynamicSharedMemorySize, 131072);
        s_attr = true;
    }

    // CSR build (ws re-poisoned each call -> deg must be zeroed here)
    zero_kernel<<<(N + 255) / 256, 256, 0, stream>>>(deg, N);
    count_kernel<<<(E + 255) / 256, 256, 0, stream>>>(ei, deg, E);
    scan_kernel<<<1, 1024, 0, stream>>>(deg, offsets, cursor, deginv, N);
    fill_kernel<<<(E + 255) / 256, 256, 0, stream>>>(ei, cursor, csr, E);

    // embed + layer-0 BN directly into Acat (no f32 x round-trip)
    embed_bn_kernel<<<(N * 128 + 255) / 256, 256, 0, stream>>>(
        tokens, posi, vemb, pemb, gamma, beta, mean, var, Acat, N);

    const int mt  = (N + 255) >> 8;    // 256-row tiles (79)
    const int rpx = (mt + 7) >> 3;     // row-tiles per XCD (10)
    const int gb  = 8 * rpx * 2;       // grid (160; tail blocks exit early)

    for (int l = 0; l < 4; ++l) {
        const int last = (l == 3);
        castW_kernel<<<1024, 256, 0, stream>>>(Wroot + (size_t)l * 262144,
                                               Wrel + (size_t)l * 262144, Wcat);
        aggregate_kernel<<<(N + 3) / 4, 256, 0, stream>>>(Acat, offsets, csr, deginv, N);
        gemm_8ph<<<gb, 512, 131072, stream>>>(
            (const unsigned short*)Acat, (const unsigned short*)Wcat, brel + l * 512,
            gamma + (l + 1) * 512, beta + (l + 1) * 512,
            mean + (l + 1) * 512, var + (l + 1) * 512,
            last, out, (unsigned short*)Acat, N, mt, rpx);
    }
}